// Round 4
// baseline (106.562 us; speedup 1.0000x reference)
//
#include <hip/hip_runtime.h>

// Poincare contrastive loss, N=4096, D=8, TEMP=0.5.
// sim[i][j] = 1/(1+arcosh(x_ij)), x_ij = 1 + 2*sqdist/((1-sqc_i)(1-sqc_j))
// Rewrite: x = 1 + P_i . Q_j  (10-term dot)
//   Q_j = [z_j(8), inv_j, inv_j*raw_j],  inv = 1/(1-min(raw,BOUNDARY))
//   P_i = [-4*inv_i*z_i(8), 2*inv_i*raw_i, 2*inv_i]
// loss = mean_i -(2*sim[i,partner] - log(sum_{j!=i} exp(2*sim[i][j])))
// Self term included in the sum, exp(2) subtracted in the epilogue.
// 3 stream ops total: memset(denom) -> pair (prep fused) -> reduce (1 block).

#define D 8
#define QS 12                // padded Q stride (floats) -> 48B, 16B-aligned
#define TWO_N 8192
#define HALF_N 4096
constexpr int BLOCK = 256;
constexpr int R     = 4;     // rows per thread
constexpr int JC    = 32;    // j-chunk staged in LDS per block
#define BOUNDARY (1.0f - 1e-5f)
#define LN2 0.6931471805599453f
#define TWO_LOG2E 2.8853900817779268f   // 2*log2(e)
#define E2 7.38905609893065f            // exp(2): self term

__device__ __forceinline__ float frcp(float x)  { return __builtin_amdgcn_rcpf(x); }
__device__ __forceinline__ float fsqrt(float x) { return __builtin_amdgcn_sqrtf(x); }
__device__ __forceinline__ float flog2(float x) { return __builtin_amdgcn_logf(x); }
__device__ __forceinline__ float fexp2(float x) { return __builtin_amdgcn_exp2f(x); }

__device__ __forceinline__ const float* zrow(const float* zi, const float* zj, int row) {
    return (row < HALF_N) ? (zi + (size_t)row * D) : (zj + (size_t)(row - HALF_N) * D);
}

// ---- pair kernel (prep fused): denom[i] += sum_j exp(2*sim(i,j)) ----
__global__ __launch_bounds__(BLOCK, 8) void pair_kernel(
    const float* __restrict__ zi, const float* __restrict__ zj,
    float* __restrict__ denom)
{
    __shared__ float sq[JC * QS];       // 1.5 KB

    const int tid   = threadIdx.x;
    const int ibase = blockIdx.x * (BLOCK * R);   // 8 i-blocks of 1024 rows
    const int jbase = blockIdx.y * JC;            // 256 j-chunks of 32

    // ---- inline prep of j-chunk Q into LDS (threads 0..JC-1) ----
    if (tid < JC) {
        const float* src = zrow(zi, zj, jbase + tid);
        float4 a = *(const float4*)(src);
        float4 b = *(const float4*)(src + 4);
        float raw = a.x*a.x + a.y*a.y + a.z*a.z + a.w*a.w
                  + b.x*b.x + b.y*b.y + b.z*b.z + b.w*b.w;
        float inv = frcp(1.0f - fminf(raw, BOUNDARY));
        float* dst = sq + tid * QS;
        *(float4*)(dst)     = a;
        *(float4*)(dst + 4) = b;
        *(float4*)(dst + 8) = make_float4(inv, inv * raw, 0.0f, 0.0f);
    }

    // ---- own rows: read z directly, build P in registers ----
    float p[R][10];
    float acc[R];
    #pragma unroll
    for (int r = 0; r < R; ++r) {
        const float* src = zrow(zi, zj, ibase + tid + r * BLOCK);
        float4 a = *(const float4*)(src);
        float4 b = *(const float4*)(src + 4);
        float raw = a.x*a.x + a.y*a.y + a.z*a.z + a.w*a.w
                  + b.x*b.x + b.y*b.y + b.z*b.z + b.w*b.w;
        float inv = frcp(1.0f - fminf(raw, BOUNDARY));
        const float m = -4.0f * inv;
        p[r][0] = m * a.x; p[r][1] = m * a.y; p[r][2] = m * a.z; p[r][3] = m * a.w;
        p[r][4] = m * b.x; p[r][5] = m * b.y; p[r][6] = m * b.z; p[r][7] = m * b.w;
        p[r][8] = 2.0f * inv * raw;               // pairs with inv_j
        p[r][9] = 2.0f * inv;                     // pairs with inv_j*raw_j
        acc[r] = 0.0f;
    }
    __syncthreads();

    #pragma unroll 2
    for (int jj = 0; jj < JC; ++jj) {
        const float* qq = sq + jj * QS;
        float4 a = *(const float4*)(qq);          // broadcast, 16B-aligned
        float4 b = *(const float4*)(qq + 4);
        float2 c = *(const float2*)(qq + 8);      // inv_j, inv_j*raw_j
        #pragma unroll
        for (int r = 0; r < R; ++r) {
            float x = 1.0f;
            x = fmaf(p[r][0], a.x, x); x = fmaf(p[r][1], a.y, x);
            x = fmaf(p[r][2], a.z, x); x = fmaf(p[r][3], a.w, x);
            x = fmaf(p[r][4], b.x, x); x = fmaf(p[r][5], b.y, x);
            x = fmaf(p[r][6], b.z, x); x = fmaf(p[r][7], b.w, x);
            x = fmaf(p[r][8], c.x, x); x = fmaf(p[r][9], c.y, x);
            float t = fmaf(x, x, -1.0f);
            float s = fsqrt(fmaxf(t, 0.0f));
            float l = flog2(x + s);               // log2(arcosh arg)
            float dd = fmaf(l, LN2, 1.0f);        // 1 + dist
            float sim = frcp(dd);
            float e = fexp2(sim * TWO_LOG2E);     // exp(2*sim)
            acc[r] += e;
        }
    }

    #pragma unroll
    for (int r = 0; r < R; ++r)
        atomicAdd(&denom[ibase + tid + r * BLOCK], acc[r]);
}

// ---- epilogue: one block, 1024 threads, 8 rows each; single plain store ----
__global__ __launch_bounds__(1024) void reduce_kernel(
    const float* __restrict__ zi, const float* __restrict__ zj,
    const float* __restrict__ denom, float* __restrict__ out)
{
    __shared__ float s_red[1024];
    const int tid = threadIdx.x;
    float acc = 0.0f;
    for (int i = tid; i < TWO_N; i += 1024) {
        const int base = (i < HALF_N) ? i : (i - HALF_N);
        const float* pa = (i < HALF_N) ? (zi + (size_t)base * D) : (zj + (size_t)base * D);
        const float* pb = (i < HALF_N) ? (zj + (size_t)base * D) : (zi + (size_t)base * D);
        float4 a0 = *(const float4*)(pa), a1 = *(const float4*)(pa + 4);
        float4 b0 = *(const float4*)(pb), b1 = *(const float4*)(pb + 4);
        float rawa = a0.x*a0.x + a0.y*a0.y + a0.z*a0.z + a0.w*a0.w
                   + a1.x*a1.x + a1.y*a1.y + a1.z*a1.z + a1.w*a1.w;
        float rawb = b0.x*b0.x + b0.y*b0.y + b0.z*b0.z + b0.w*b0.w
                   + b1.x*b1.x + b1.y*b1.y + b1.z*b1.z + b1.w*b1.w;
        float dot  = a0.x*b0.x + a0.y*b0.y + a0.z*b0.z + a0.w*b0.w
                   + a1.x*b1.x + a1.y*b1.y + a1.z*b1.z + a1.w*b1.w;
        float sqd  = fmaxf(rawa + rawb - 2.0f * dot, 0.0f);
        float inva = frcp(1.0f - fminf(rawa, BOUNDARY));
        float invb = frcp(1.0f - fminf(rawb, BOUNDARY));
        float x    = fmaf(2.0f * sqd, inva * invb, 1.0f);
        float t    = fmaf(x, x, -1.0f);
        float s    = fsqrt(fmaxf(t, 0.0f));
        float dist = flog2(x + s) * LN2;
        float sim  = frcp(1.0f + dist);           // positive pair similarity
        float dlog = flog2(denom[i] - E2) * LN2;  // ln(denom excl. self)
        acc += -(2.0f * sim - dlog);
    }
    s_red[tid] = acc;
    __syncthreads();
    for (int off = 512; off > 0; off >>= 1) {
        if (tid < off) s_red[tid] += s_red[tid + off];
        __syncthreads();
    }
    if (tid == 0) out[0] = s_red[0] * (1.0f / (float)TWO_N);
}

extern "C" void kernel_launch(void* const* d_in, const int* in_sizes, int n_in,
                              void* d_out, int out_size, void* d_ws, size_t ws_size,
                              hipStream_t stream) {
    const float* zi = (const float*)d_in[0];
    const float* zj = (const float*)d_in[1];

    float* denom = (float*)d_ws;                  // [8192]

    hipMemsetAsync(denom, 0, (size_t)TWO_N * sizeof(float), stream);

    dim3 grid(TWO_N / (BLOCK * R), TWO_N / JC);   // 8 x 256 = 2048 blocks
    pair_kernel<<<grid, BLOCK, 0, stream>>>(zi, zj, denom);

    reduce_kernel<<<1, 1024, 0, stream>>>(zi, zj, denom, (float*)d_out);
}

// Round 5
// 106.290 us; speedup vs baseline: 1.0026x; 1.0026x over previous
//
#include <hip/hip_runtime.h>

// Poincare contrastive loss, N=4096, D=8, TEMP=0.5.
// sim[i][j] = 1/(1+arcosh(x_ij)), x_ij = 1 + 2*sqdist/((1-sqc_i)(1-sqc_j))
// Rewrite: x = 1 + P_i . Q_j  (10-term dot)
//   Q_j = [z_j(8), inv_j, inv_j*raw_j],  inv = 1/(1-min(raw,BOUNDARY))
//   P_i = [-4*inv_i*z_i(8), 2*inv_i*raw_i, 2*inv_i]
// loss = mean_i -(2*sim[i,partner] - log(sum_{j!=i} exp(2*sim[i][j])))
//
// SYMMETRY: e(i,j)=e(j,i). Only tiles with j-chunk >= i-block are computed;
// each pair (i<j) contributes to denom[i] (register acc) and denom[j]
// (wave shfl_xor reduce -> LDS accumulator -> 1 atomic per (block,j)).
// Strict j>i mask on diagonal tiles excludes the self term exactly.

#define D 8
#define QS 12                // padded Q stride (floats) -> 48B, 16B-aligned
#define TWO_N 8192
#define HALF_N 4096
constexpr int BLOCK = 256;
constexpr int R     = 4;     // rows per thread -> i-tile = 1024
constexpr int JC    = 32;    // j-chunk staged in LDS per block
#define BOUNDARY (1.0f - 1e-5f)
#define LN2 0.6931471805599453f
#define TWO_LOG2E 2.8853900817779268f   // 2*log2(e)
#define NTILE 1152           // sum_{b=0}^{7} (256 - 32*b)

__device__ __forceinline__ float frcp(float x)  { return __builtin_amdgcn_rcpf(x); }
__device__ __forceinline__ float fsqrt(float x) { return __builtin_amdgcn_sqrtf(x); }
__device__ __forceinline__ float flog2(float x) { return __builtin_amdgcn_logf(x); }
__device__ __forceinline__ float fexp2(float x) { return __builtin_amdgcn_exp2f(x); }

// ---- build Q[row] = [z(8), inv, inv*raw, 0, 0] ----
__global__ __launch_bounds__(256) void prep_kernel(
    const float* __restrict__ zi, const float* __restrict__ zj,
    float* __restrict__ q)
{
    const int row = blockIdx.x * 256 + threadIdx.x;
    const float* src = (row < HALF_N) ? (zi + (size_t)row * D)
                                      : (zj + (size_t)(row - HALF_N) * D);
    float4 a = *(const float4*)(src);
    float4 b = *(const float4*)(src + 4);
    float raw = a.x*a.x + a.y*a.y + a.z*a.z + a.w*a.w
              + b.x*b.x + b.y*b.y + b.z*b.z + b.w*b.w;
    float inv = frcp(1.0f - fminf(raw, BOUNDARY));
    float* dst = q + (size_t)row * QS;
    *(float4*)(dst)     = a;
    *(float4*)(dst + 4) = b;
    *(float4*)(dst + 8) = make_float4(inv, inv * raw, 0.0f, 0.0f);
}

// ---- symmetric pair kernel ----
__global__ __launch_bounds__(BLOCK, 6) void pair_kernel(
    const float* __restrict__ q, float* __restrict__ denom)
{
    __shared__ float sq[JC * QS];       // 1.5 KB j-chunk Q
    __shared__ float sdenom[JC];        // column accumulators

    const int tid = threadIdx.x;

    // linear tile id -> (b, c): b = i-block (1024 rows), c = j-chunk (32 rows)
    int t = blockIdx.x, b = 0;
    #pragma unroll
    for (int k = 0; k < 8; ++k) {
        int cnt = 256 - 32 * k;
        if (t >= cnt && k < 7) { t -= cnt; b = k + 1; }
        else break;
    }
    const int ibase = b * 1024;
    const int jbase = (32 * b + t) * 32;
    const bool diag = (jbase < ibase + 1024);   // wave-uniform

    // stage j-chunk Q (96 float4) + zero column accumulators
    if (tid < JC * QS / 4)
        ((float4*)sq)[tid] = ((const float4*)(q + (size_t)jbase * QS))[tid];
    if (tid < JC) sdenom[tid] = 0.0f;

    // own rows -> P in registers
    float p[R][10];
    float acc[R];
    int   irow[R];
    #pragma unroll
    for (int r = 0; r < R; ++r) {
        irow[r] = ibase + tid + r * BLOCK;
        const float* qr = q + (size_t)irow[r] * QS;
        float4 a = *(const float4*)(qr);
        float4 bb = *(const float4*)(qr + 4);
        float4 c = *(const float4*)(qr + 8);      // c.x=inv, c.y=inv*raw
        const float m = -4.0f * c.x;
        p[r][0] = m * a.x;  p[r][1] = m * a.y;  p[r][2] = m * a.z;  p[r][3] = m * a.w;
        p[r][4] = m * bb.x; p[r][5] = m * bb.y; p[r][6] = m * bb.z; p[r][7] = m * bb.w;
        p[r][8] = 2.0f * c.y;
        p[r][9] = 2.0f * c.x;
        acc[r] = 0.0f;
    }
    __syncthreads();

    #pragma unroll 2
    for (int jj = 0; jj < JC; ++jj) {
        const float* qq = sq + jj * QS;
        float4 a = *(const float4*)(qq);          // broadcast, 16B-aligned
        float4 bb = *(const float4*)(qq + 4);
        float2 c = *(const float2*)(qq + 8);
        const int j = jbase + jj;

        float ecol = 0.0f;
        #pragma unroll
        for (int r = 0; r < R; ++r) {
            float x = 1.0f;
            x = fmaf(p[r][0], a.x, x);  x = fmaf(p[r][1], a.y, x);
            x = fmaf(p[r][2], a.z, x);  x = fmaf(p[r][3], a.w, x);
            x = fmaf(p[r][4], bb.x, x); x = fmaf(p[r][5], bb.y, x);
            x = fmaf(p[r][6], bb.z, x); x = fmaf(p[r][7], bb.w, x);
            x = fmaf(p[r][8], c.x, x);  x = fmaf(p[r][9], c.y, x);
            float tt = fmaf(x, x, -1.0f);
            float s  = fsqrt(fmaxf(tt, 0.0f));
            float l  = flog2(x + s);
            float dd = fmaf(l, LN2, 1.0f);        // 1 + arcosh
            float sim = frcp(dd);
            float e  = fexp2(sim * TWO_LOG2E);    // exp(2*sim)
            if (diag) e = (j > irow[r]) ? e : 0.0f;   // strict upper triangle
            acc[r] += e;
            ecol   += e;
        }
        // wave reduction of ecol -> lane 0, then LDS accumulate for denom[j]
        #pragma unroll
        for (int m = 1; m < 64; m <<= 1)
            ecol += __shfl_xor(ecol, m, 64);
        if ((tid & 63) == 0) atomicAdd(&sdenom[jj], ecol);
    }

    __syncthreads();
    if (tid < JC) atomicAdd(&denom[jbase + tid], sdenom[tid]);
    #pragma unroll
    for (int r = 0; r < R; ++r)
        atomicAdd(&denom[irow[r]], acc[r]);
}

// ---- epilogue: one block, 1024 threads; denom already excludes self ----
__global__ __launch_bounds__(1024) void reduce_kernel(
    const float* __restrict__ zi, const float* __restrict__ zj,
    const float* __restrict__ denom, float* __restrict__ out)
{
    __shared__ float s_red[1024];
    const int tid = threadIdx.x;
    float acc = 0.0f;
    for (int i = tid; i < TWO_N; i += 1024) {
        const int base = (i < HALF_N) ? i : (i - HALF_N);
        const float* pa = (i < HALF_N) ? (zi + (size_t)base * D) : (zj + (size_t)base * D);
        const float* pb = (i < HALF_N) ? (zj + (size_t)base * D) : (zi + (size_t)base * D);
        float4 a0 = *(const float4*)(pa), a1 = *(const float4*)(pa + 4);
        float4 b0 = *(const float4*)(pb), b1 = *(const float4*)(pb + 4);
        float rawa = a0.x*a0.x + a0.y*a0.y + a0.z*a0.z + a0.w*a0.w
                   + a1.x*a1.x + a1.y*a1.y + a1.z*a1.z + a1.w*a1.w;
        float rawb = b0.x*b0.x + b0.y*b0.y + b0.z*b0.z + b0.w*b0.w
                   + b1.x*b1.x + b1.y*b1.y + b1.z*b1.z + b1.w*b1.w;
        float dot  = a0.x*b0.x + a0.y*b0.y + a0.z*b0.z + a0.w*b0.w
                   + a1.x*b1.x + a1.y*b1.y + a1.z*b1.z + a1.w*b1.w;
        float sqd  = fmaxf(rawa + rawb - 2.0f * dot, 0.0f);
        float inva = frcp(1.0f - fminf(rawa, BOUNDARY));
        float invb = frcp(1.0f - fminf(rawb, BOUNDARY));
        float x    = fmaf(2.0f * sqd, inva * invb, 1.0f);
        float t    = fmaf(x, x, -1.0f);
        float s    = fsqrt(fmaxf(t, 0.0f));
        float dist = flog2(x + s) * LN2;
        float sim  = frcp(1.0f + dist);           // positive pair similarity
        float dlog = flog2(denom[i]) * LN2;       // self already excluded
        acc += -(2.0f * sim - dlog);
    }
    s_red[tid] = acc;
    __syncthreads();
    for (int off = 512; off > 0; off >>= 1) {
        if (tid < off) s_red[tid] += s_red[tid + off];
        __syncthreads();
    }
    if (tid == 0) out[0] = s_red[0] * (1.0f / (float)TWO_N);
}

extern "C" void kernel_launch(void* const* d_in, const int* in_sizes, int n_in,
                              void* d_out, int out_size, void* d_ws, size_t ws_size,
                              hipStream_t stream) {
    const float* zi = (const float*)d_in[0];
    const float* zj = (const float*)d_in[1];

    float* denom = (float*)d_ws;                  // [8192]
    float* q     = denom + TWO_N;                 // [8192 * 12]

    hipMemsetAsync(denom, 0, (size_t)TWO_N * sizeof(float), stream);

    prep_kernel<<<TWO_N / 256, 256, 0, stream>>>(zi, zj, q);

    pair_kernel<<<NTILE, BLOCK, 0, stream>>>(q, denom);

    reduce_kernel<<<1, 1024, 0, stream>>>(zi, zj, denom, (float*)d_out);
}